// Round 1
// baseline (799.045 us; speedup 1.0000x reference)
//
#include <hip/hip_runtime.h>
#include <math.h>

#define N_NODES 50000
#define N_EDGES 800000
#define N_GRAPHS 64

__device__ __forceinline__ float leaky(float v){ return v > 0.f ? v : 0.2f*v; }
__device__ __forceinline__ float elu1(float v){ return v > 0.f ? v : expm1f(v); }

// ---- lin1: xl = x@Wl, xr = x@Wr ; x [N,64], W [64,256] -> out [N,256]
__global__ __launch_bounds__(256) void k_lin1(const float* __restrict__ x,
        const float* __restrict__ Wl, const float* __restrict__ Wr,
        float* __restrict__ xl, float* __restrict__ xr){
    __shared__ float xs[16][64];
    int t = threadIdx.x;
    size_t n0 = (size_t)blockIdx.x * 16;
    const float4* xg = (const float4*)(x + n0*64);   // 1024 floats = 256 float4
    ((float4*)xs)[t] = xg[t];
    __syncthreads();
    float accl[16], accr[16];
    #pragma unroll
    for (int m=0;m<16;m++){ accl[m]=0.f; accr[m]=0.f; }
    for (int k=0;k<64;k++){
        float wl = Wl[k*256+t], wr = Wr[k*256+t];
        #pragma unroll
        for (int m=0;m<16;m++){ float xv = xs[m][k]; accl[m]=fmaf(xv,wl,accl[m]); accr[m]=fmaf(xv,wr,accr[m]); }
    }
    for (int m=0;m<16;m++){
        xl[(n0+m)*256+t]=accl[m];
        xr[(n0+m)*256+t]=accr[m];
    }
}

// ---- lin2: h [N,256] (already bias+ELU'd), W [256,64] -> out [N,64]
__global__ __launch_bounds__(128) void k_lin2(const float* __restrict__ h,
        const float* __restrict__ Wl, const float* __restrict__ Wr,
        float* __restrict__ xl, float* __restrict__ xr){
    __shared__ float hs[16][256];
    int t = threadIdx.x;
    size_t n0 = (size_t)blockIdx.x * 16;
    const float4* hg = (const float4*)(h + n0*256);  // 4096 floats = 1024 float4
    #pragma unroll
    for (int i=0;i<8;i++) ((float4*)hs)[t + 128*i] = hg[t + 128*i];
    __syncthreads();
    const float* W = (t < 64) ? Wl : Wr;
    float* o = (t < 64) ? xl : xr;
    int col = t & 63;
    float acc[16];
    #pragma unroll
    for (int m=0;m<16;m++) acc[m]=0.f;
    for (int k=0;k<256;k++){
        float w = W[k*64+col];
        #pragma unroll
        for (int m=0;m<16;m++) acc[m]=fmaf(hs[m][k],w,acc[m]);
    }
    for (int m=0;m<16;m++) o[(n0+m)*64+col]=acc[m];
}

// ---- CSR build over dst
__global__ void k_hist(const int* __restrict__ ei, int* __restrict__ deg){
    int e = blockIdx.x*256 + threadIdx.x;
    if (e < N_EDGES) atomicAdd(&deg[ei[N_EDGES + e]], 1);
}

__global__ __launch_bounds__(1024) void k_scan_a(const int* __restrict__ deg,
        int* __restrict__ rowptr, int* __restrict__ partial){
    __shared__ int s[1024];
    int t = threadIdx.x; int i = blockIdx.x*1024 + t;
    int v = (i < N_NODES) ? deg[i] : 0;
    s[t] = v; __syncthreads();
    for (int off=1; off<1024; off<<=1){
        int add = (t>=off) ? s[t-off] : 0;
        __syncthreads();
        s[t] += add;
        __syncthreads();
    }
    if (i < N_NODES) rowptr[i] = s[t] - v;   // local exclusive
    if (t == 1023) partial[blockIdx.x] = s[1023];
}

__global__ void k_scan_b(int* partial, int nblk){
    if (threadIdx.x == 0){
        int run = 0;
        for (int b=0;b<nblk;b++){ int v = partial[b]; partial[b] = run; run += v; }
    }
}

__global__ __launch_bounds__(1024) void k_scan_c(int* __restrict__ rowptr,
        int* __restrict__ cursor, const int* __restrict__ partial){
    int i = blockIdx.x*1024 + threadIdx.x;
    if (i < N_NODES){
        int r = rowptr[i] + partial[blockIdx.x];
        rowptr[i] = r; cursor[i] = r;
    } else if (i == N_NODES){
        rowptr[N_NODES] = N_EDGES;
    }
}

__global__ void k_scatter(const int* __restrict__ ei, int* __restrict__ cursor,
                          int* __restrict__ perm){
    int e = blockIdx.x*256 + threadIdx.x;
    if (e < N_EDGES){
        int d = ei[N_EDGES + e];
        int pos = atomicAdd(&cursor[d], 1);
        perm[pos] = e;
    }
}

// ---- fused GAT layer 1: per dst-node block (256 threads = 4 heads x 64 ch)
// out = elu( (sum_e exp(l_e)*xl[src_e]) / (sum_e exp(l_e) + eps) + b )
__global__ __launch_bounds__(256) void k_gat1(const float* __restrict__ xl,
        const float* __restrict__ xr, const int* __restrict__ ei,
        const int* __restrict__ rowptr, const int* __restrict__ perm,
        const float* __restrict__ att, const float* __restrict__ b,
        float* __restrict__ h1){
    int n = blockIdx.x, t = threadIdx.x;
    float xr_t  = xr[(size_t)n*256 + t];
    float att_t = att[t];                 // [4][64] flat == t
    float acc = 0.f, dacc = 0.f;
    int beg = rowptr[n], end = rowptr[n+1];
    for (int j=beg; j<end; j++){
        int e = perm[j];
        int s = ei[e];                    // src
        float xlv = xl[(size_t)s*256 + t];
        float p = leaky(xlv + xr_t) * att_t;
        #pragma unroll
        for (int off=32; off; off>>=1) p += __shfl_xor(p, off);  // wave = head
        float ex = expf(p);
        acc = fmaf(ex, xlv, acc);
        dacc += ex;
    }
    float o = acc / (dacc + 1e-16f) + b[t];
    h1[(size_t)n*256 + t] = elu1(o);
}

// ---- fused GAT layer 2: one wave per dst node (64 ch, 1 head)
__global__ __launch_bounds__(256) void k_gat2(const float* __restrict__ xl,
        const float* __restrict__ xr, const int* __restrict__ ei,
        const int* __restrict__ rowptr, const int* __restrict__ perm,
        const float* __restrict__ att, const float* __restrict__ b,
        float* __restrict__ h2){
    int wave = threadIdx.x >> 6, l = threadIdx.x & 63;
    int n = blockIdx.x*4 + wave;
    if (n >= N_NODES) return;
    float xr_t  = xr[(size_t)n*64 + l];
    float att_t = att[l];
    float acc = 0.f, dacc = 0.f;
    int beg = rowptr[n], end = rowptr[n+1];
    for (int j=beg; j<end; j++){
        int e = perm[j];
        int s = ei[e];
        float xlv = xl[(size_t)s*64 + l];
        float p = leaky(xlv + xr_t) * att_t;
        #pragma unroll
        for (int off=32; off; off>>=1) p += __shfl_xor(p, off);
        float ex = expf(p);
        acc = fmaf(ex, xlv, acc);
        dacc += ex;
    }
    float o = acc / (dacc + 1e-16f) + b[l];
    h2[(size_t)n*64 + l] = elu1(o);
}

__device__ __forceinline__ int lower_bound_i(const int* a, int n, int key){
    int lo = 0, hi = n;
    while (lo < hi){ int mid = (lo+hi)>>1; if (a[mid] < key) lo = mid+1; else hi = mid; }
    return lo;
}

// ---- global mean pool: one block per graph (batch is sorted)
__global__ __launch_bounds__(256) void k_pool(const float* __restrict__ h2,
        const int* __restrict__ batch, float* __restrict__ pooled){
    int g = blockIdx.x, t = threadIdx.x;
    int c = t & 63, q = t >> 6;
    int start = lower_bound_i(batch, N_NODES, g);
    int end   = lower_bound_i(batch, N_NODES, g+1);
    float s = 0.f;
    for (int i = start + q; i < end; i += 4) s += h2[(size_t)i*64 + c];
    __shared__ float red[256];
    red[t] = s; __syncthreads();
    if (q == 0){
        float tot = red[c] + red[64+c] + red[128+c] + red[192+c];
        int cnt = end - start;
        pooled[g*64 + c] = tot / fmaxf((float)cnt, 1.f);
    }
}

// ---- MLP head: one block per graph
__global__ __launch_bounds__(64) void k_mlp(const float* __restrict__ pooled,
        const float* __restrict__ W3, const float* __restrict__ b3,
        const float* __restrict__ W4, const float* __restrict__ b4,
        float* __restrict__ out){
    int g = blockIdx.x, t = threadIdx.x;
    __shared__ float ps[64], zs[64];
    ps[t] = pooled[g*64 + t]; __syncthreads();
    float a = b3[t];
    for (int k=0;k<64;k++) a = fmaf(ps[k], W3[k*64+t], a);
    zs[t] = fmaxf(a, 0.f); __syncthreads();
    if (t < 2){
        float o = b4[t];
        for (int k=0;k<64;k++) o = fmaf(zs[k], W4[k*2+t], o);
        out[g*2 + t] = o;
    }
}

extern "C" void kernel_launch(void* const* d_in, const int* in_sizes, int n_in,
                              void* d_out, int out_size, void* d_ws, size_t ws_size,
                              hipStream_t stream) {
    const float* x    = (const float*)d_in[0];
    const int*   ei   = (const int*)  d_in[1];   // [2, E] flat
    const int*   batch= (const int*)  d_in[2];
    const float* Wl1  = (const float*)d_in[3];
    const float* Wr1  = (const float*)d_in[4];
    const float* att1 = (const float*)d_in[5];
    const float* b1   = (const float*)d_in[6];
    const float* Wl2  = (const float*)d_in[7];
    const float* Wr2  = (const float*)d_in[8];
    const float* att2 = (const float*)d_in[9];
    const float* b2   = (const float*)d_in[10];
    const float* W3   = (const float*)d_in[11];
    const float* b3   = (const float*)d_in[12];
    const float* W4   = (const float*)d_in[13];
    const float* b4   = (const float*)d_in[14];
    float* out = (float*)d_out;

    // workspace layout
    float* xl1 = (float*)d_ws;                          // [N,256]
    float* xr1 = xl1 + (size_t)N_NODES*256;             // [N,256]
    float* h1  = xr1 + (size_t)N_NODES*256;             // [N,256]
    // layer-2 buffers overlay xl1 (dead after k_gat1)
    float* xl2 = xl1;                                   // [N,64]
    float* xr2 = xl2 + (size_t)N_NODES*64;              // [N,64]
    float* h2  = xr2 + (size_t)N_NODES*64;              // [N,64]
    float* pooled = h2 + (size_t)N_NODES*64;            // [64,64]
    int* rowptr  = (int*)(h1 + (size_t)N_NODES*256);    // [N+1]
    int* cursor  = rowptr + (N_NODES+1);                // [N]
    int* partial = cursor + N_NODES;                    // [64]
    int* perm    = partial + 64;                        // [E]
    int* deg     = perm + N_EDGES;                      // [N]

    hipMemsetAsync(deg, 0, (size_t)N_NODES*sizeof(int), stream);

    k_lin1<<<N_NODES/16, 256, 0, stream>>>(x, Wl1, Wr1, xl1, xr1);

    k_hist<<<N_EDGES/256, 256, 0, stream>>>(ei, deg);
    const int SCAN_BLKS = (N_NODES + 1023) / 1024;      // 49
    k_scan_a<<<SCAN_BLKS, 1024, 0, stream>>>(deg, rowptr, partial);
    k_scan_b<<<1, 64, 0, stream>>>(partial, SCAN_BLKS);
    k_scan_c<<<SCAN_BLKS, 1024, 0, stream>>>(rowptr, cursor, partial);
    k_scatter<<<N_EDGES/256, 256, 0, stream>>>(ei, cursor, perm);

    k_gat1<<<N_NODES, 256, 0, stream>>>(xl1, xr1, ei, rowptr, perm, att1, b1, h1);
    k_lin2<<<N_NODES/16, 128, 0, stream>>>(h1, Wl2, Wr2, xl2, xr2);
    k_gat2<<<(N_NODES+3)/4, 256, 0, stream>>>(xl2, xr2, ei, rowptr, perm, att2, b2, h2);
    k_pool<<<N_GRAPHS, 256, 0, stream>>>(h2, batch, pooled);
    k_mlp<<<N_GRAPHS, 64, 0, stream>>>(pooled, W3, b3, W4, b4, out);
}

// Round 2
// 462.957 us; speedup vs baseline: 1.7260x; 1.7260x over previous
//
#include <hip/hip_runtime.h>
#include <math.h>

#define N_NODES 50000
#define N_EDGES 800000
#define N_GRAPHS 64

__device__ __forceinline__ float leaky(float v){ return v > 0.f ? v : 0.2f*v; }
__device__ __forceinline__ float elu1(float v){ return v > 0.f ? v : expm1f(v); }

// ---- lin1: xl = x@Wl, xr = x@Wr ; x [N,64], W [64,256] -> out [N,256]
__global__ __launch_bounds__(256) void k_lin1(const float* __restrict__ x,
        const float* __restrict__ Wl, const float* __restrict__ Wr,
        float* __restrict__ xl, float* __restrict__ xr){
    __shared__ float xs[16][64];
    int t = threadIdx.x;
    size_t n0 = (size_t)blockIdx.x * 16;
    const float4* xg = (const float4*)(x + n0*64);   // 1024 floats = 256 float4
    ((float4*)xs)[t] = xg[t];
    __syncthreads();
    float accl[16], accr[16];
    #pragma unroll
    for (int m=0;m<16;m++){ accl[m]=0.f; accr[m]=0.f; }
    for (int k=0;k<64;k++){
        float wl = Wl[k*256+t], wr = Wr[k*256+t];
        #pragma unroll
        for (int m=0;m<16;m++){ float xv = xs[m][k]; accl[m]=fmaf(xv,wl,accl[m]); accr[m]=fmaf(xv,wr,accr[m]); }
    }
    for (int m=0;m<16;m++){
        xl[(n0+m)*256+t]=accl[m];
        xr[(n0+m)*256+t]=accr[m];
    }
}

// ---- lin2: h [N,256] (already bias+ELU'd), W [256,64] -> out [N,64]
__global__ __launch_bounds__(128) void k_lin2(const float* __restrict__ h,
        const float* __restrict__ Wl, const float* __restrict__ Wr,
        float* __restrict__ xl, float* __restrict__ xr){
    __shared__ float hs[16][256];
    int t = threadIdx.x;
    size_t n0 = (size_t)blockIdx.x * 16;
    const float4* hg = (const float4*)(h + n0*256);  // 4096 floats = 1024 float4
    #pragma unroll
    for (int i=0;i<8;i++) ((float4*)hs)[t + 128*i] = hg[t + 128*i];
    __syncthreads();
    const float* W = (t < 64) ? Wl : Wr;
    float* o = (t < 64) ? xl : xr;
    int col = t & 63;
    float acc[16];
    #pragma unroll
    for (int m=0;m<16;m++) acc[m]=0.f;
    for (int k=0;k<256;k++){
        float w = W[k*64+col];
        #pragma unroll
        for (int m=0;m<16;m++) acc[m]=fmaf(hs[m][k],w,acc[m]);
    }
    for (int m=0;m<16;m++) o[(n0+m)*64+col]=acc[m];
}

// ---- CSR build over dst (srcs stored directly: kills perm->ei dependent load)
__global__ void k_hist(const int* __restrict__ ei, int* __restrict__ deg){
    int e = blockIdx.x*256 + threadIdx.x;
    if (e < N_EDGES) atomicAdd(&deg[ei[N_EDGES + e]], 1);
}

__global__ __launch_bounds__(1024) void k_scan_a(const int* __restrict__ deg,
        int* __restrict__ rowptr, int* __restrict__ partial){
    __shared__ int s[1024];
    int t = threadIdx.x; int i = blockIdx.x*1024 + t;
    int v = (i < N_NODES) ? deg[i] : 0;
    s[t] = v; __syncthreads();
    for (int off=1; off<1024; off<<=1){
        int add = (t>=off) ? s[t-off] : 0;
        __syncthreads();
        s[t] += add;
        __syncthreads();
    }
    if (i < N_NODES) rowptr[i] = s[t] - v;   // local exclusive
    if (t == 1023) partial[blockIdx.x] = s[1023];   // block total
}

__global__ __launch_bounds__(1024) void k_scan_c(int* __restrict__ rowptr,
        int* __restrict__ cursor, const int* __restrict__ partial){
    __shared__ int base;
    if (threadIdx.x == 0){
        int run = 0;
        for (int bk=0; bk<(int)blockIdx.x; bk++) run += partial[bk];
        base = run;
    }
    __syncthreads();
    int i = blockIdx.x*1024 + threadIdx.x;
    if (i < N_NODES){
        int r = rowptr[i] + base;
        rowptr[i] = r; cursor[i] = r;
    } else if (i == N_NODES){
        rowptr[N_NODES] = N_EDGES;
    }
}

__global__ void k_scatter(const int* __restrict__ ei, int* __restrict__ cursor,
                          int* __restrict__ srcs){
    int e = blockIdx.x*256 + threadIdx.x;
    if (e < N_EDGES){
        int d = ei[N_EDGES + e];
        int pos = atomicAdd(&cursor[d], 1);
        srcs[pos] = ei[e];                    // store SRC directly
    }
}

// ---- fused GAT layer 1: block=256 (4 waves), one wave per EDGE slot.
// Lane l holds channels [4l,4l+3] (float4); head = l>>4; dot-reduce = 4 shfl
// steps within 16-lane groups. 4 edges in flight per block.
__global__ __launch_bounds__(256) void k_gat1(const float* __restrict__ xl,
        const float* __restrict__ xr, const int* __restrict__ srcs,
        const int* __restrict__ rowptr,
        const float* __restrict__ att, const float* __restrict__ b,
        float* __restrict__ h1){
    int n = blockIdx.x;
    int w = threadIdx.x >> 6, l = threadIdx.x & 63;
    float4 xr4  = ((const float4*)(xr + (size_t)n*256))[l];
    float4 att4 = ((const float4*)att)[l];
    float4 acc = make_float4(0.f,0.f,0.f,0.f);
    float dacc = 0.f;
    int beg = rowptr[n], end = rowptr[n+1];
    int j = beg + w;
    int s = (j < end) ? srcs[j] : 0;
    while (j < end){
        int jn = j + 4;
        int sn = (jn < end) ? srcs[jn] : 0;    // prefetch next src
        float4 xlv = ((const float4*)(xl + (size_t)s*256))[l];
        float p =      leaky(xlv.x + xr4.x) * att4.x;
        p = fmaf(leaky(xlv.y + xr4.y), att4.y, p);
        p = fmaf(leaky(xlv.z + xr4.z), att4.z, p);
        p = fmaf(leaky(xlv.w + xr4.w), att4.w, p);
        p += __shfl_xor(p, 1);
        p += __shfl_xor(p, 2);
        p += __shfl_xor(p, 4);
        p += __shfl_xor(p, 8);
        float ex = __expf(p);
        acc.x = fmaf(ex, xlv.x, acc.x);
        acc.y = fmaf(ex, xlv.y, acc.y);
        acc.z = fmaf(ex, xlv.z, acc.z);
        acc.w = fmaf(ex, xlv.w, acc.w);
        dacc += ex;
        s = sn; j = jn;
    }
    __shared__ float4 sacc[4][64];
    __shared__ float  sd[4][64];
    sacc[w][l] = acc; sd[w][l] = dacc;
    __syncthreads();
    if (w == 0){
        float4 a0 = sacc[0][l], a1 = sacc[1][l], a2 = sacc[2][l], a3 = sacc[3][l];
        float d = sd[0][l] + sd[1][l] + sd[2][l] + sd[3][l];
        float inv = 1.f / (d + 1e-16f);
        float4 b4 = ((const float4*)b)[l];
        float4 o;
        o.x = elu1(fmaf(a0.x + a1.x + a2.x + a3.x, inv, b4.x));
        o.y = elu1(fmaf(a0.y + a1.y + a2.y + a3.y, inv, b4.y));
        o.z = elu1(fmaf(a0.z + a1.z + a2.z + a3.z, inv, b4.z));
        o.w = elu1(fmaf(a0.w + a1.w + a2.w + a3.w, inv, b4.w));
        ((float4*)(h1 + (size_t)n*256))[l] = o;
    }
}

// ---- fused GAT layer 2: one wave per node; 4 edge-slots per wave
// (16 lanes x float4 = 64 channels per edge). Cross-slot combine via shfl.
__global__ __launch_bounds__(256) void k_gat2(const float* __restrict__ xl,
        const float* __restrict__ xr, const int* __restrict__ srcs,
        const int* __restrict__ rowptr,
        const float* __restrict__ att, const float* __restrict__ b,
        float* __restrict__ h2){
    int w = threadIdx.x >> 6, l = threadIdx.x & 63;
    int n = blockIdx.x*4 + w;
    int g = l >> 4, sub = l & 15;
    float4 xr4  = ((const float4*)(xr + (size_t)n*64))[sub];
    float4 att4 = ((const float4*)att)[sub];
    float4 acc = make_float4(0.f,0.f,0.f,0.f);
    float dacc = 0.f;
    int beg = rowptr[n], end = rowptr[n+1];
    for (int j = beg; j < end; j += 4){
        int jj = j + g;
        bool act = jj < end;
        int s = act ? srcs[jj] : srcs[beg];
        float4 xlv = ((const float4*)(xl + (size_t)s*64))[sub];
        float p =      leaky(xlv.x + xr4.x) * att4.x;
        p = fmaf(leaky(xlv.y + xr4.y), att4.y, p);
        p = fmaf(leaky(xlv.z + xr4.z), att4.z, p);
        p = fmaf(leaky(xlv.w + xr4.w), att4.w, p);
        p += __shfl_xor(p, 1);
        p += __shfl_xor(p, 2);
        p += __shfl_xor(p, 4);
        p += __shfl_xor(p, 8);
        float ex = act ? __expf(p) : 0.f;
        acc.x = fmaf(ex, xlv.x, acc.x);
        acc.y = fmaf(ex, xlv.y, acc.y);
        acc.z = fmaf(ex, xlv.z, acc.z);
        acc.w = fmaf(ex, xlv.w, acc.w);
        dacc += ex;
    }
    // combine the 4 edge slots (lanes differing in bits 4,5)
    #pragma unroll
    for (int off=16; off<64; off<<=1){
        acc.x += __shfl_xor(acc.x, off);
        acc.y += __shfl_xor(acc.y, off);
        acc.z += __shfl_xor(acc.z, off);
        acc.w += __shfl_xor(acc.w, off);
        dacc  += __shfl_xor(dacc,  off);
    }
    if (g == 0){
        float inv = 1.f / (dacc + 1e-16f);
        float4 b4 = ((const float4*)b)[sub];
        float4 o;
        o.x = elu1(fmaf(acc.x, inv, b4.x));
        o.y = elu1(fmaf(acc.y, inv, b4.y));
        o.z = elu1(fmaf(acc.z, inv, b4.z));
        o.w = elu1(fmaf(acc.w, inv, b4.w));
        ((float4*)(h2 + (size_t)n*64))[sub] = o;
    }
}

__device__ __forceinline__ int lower_bound_i(const int* a, int n, int key){
    int lo = 0, hi = n;
    while (lo < hi){ int mid = (lo+hi)>>1; if (a[mid] < key) lo = mid+1; else hi = mid; }
    return lo;
}

// ---- global mean pool + MLP head fused: one block per graph (batch sorted)
__global__ __launch_bounds__(256) void k_poolmlp(const float* __restrict__ h2,
        const int* __restrict__ batch,
        const float* __restrict__ W3, const float* __restrict__ b3,
        const float* __restrict__ W4, const float* __restrict__ b4,
        float* __restrict__ out){
    int g = blockIdx.x, t = threadIdx.x;
    int c = t & 63, q = t >> 6;
    int start = lower_bound_i(batch, N_NODES, g);
    int end   = lower_bound_i(batch, N_NODES, g+1);
    float s = 0.f;
    for (int i = start + q; i < end; i += 4) s += h2[(size_t)i*64 + c];
    __shared__ float red[256];
    __shared__ float ps[64], zs[64];
    red[t] = s; __syncthreads();
    if (q == 0){
        float tot = red[c] + red[64+c] + red[128+c] + red[192+c];
        ps[c] = tot / fmaxf((float)(end - start), 1.f);
    }
    __syncthreads();
    if (q == 0){
        float a = b3[c];
        for (int k=0;k<64;k++) a = fmaf(ps[k], W3[k*64+c], a);
        zs[c] = fmaxf(a, 0.f);
    }
    __syncthreads();
    if (t < 2){
        float o = b4[t];
        for (int k=0;k<64;k++) o = fmaf(zs[k], W4[k*2+t], o);
        out[g*2 + t] = o;
    }
}

extern "C" void kernel_launch(void* const* d_in, const int* in_sizes, int n_in,
                              void* d_out, int out_size, void* d_ws, size_t ws_size,
                              hipStream_t stream) {
    const float* x    = (const float*)d_in[0];
    const int*   ei   = (const int*)  d_in[1];   // [2, E] flat
    const int*   batch= (const int*)  d_in[2];
    const float* Wl1  = (const float*)d_in[3];
    const float* Wr1  = (const float*)d_in[4];
    const float* att1 = (const float*)d_in[5];
    const float* b1   = (const float*)d_in[6];
    const float* Wl2  = (const float*)d_in[7];
    const float* Wr2  = (const float*)d_in[8];
    const float* att2 = (const float*)d_in[9];
    const float* b2   = (const float*)d_in[10];
    const float* W3   = (const float*)d_in[11];
    const float* b3   = (const float*)d_in[12];
    const float* W4   = (const float*)d_in[13];
    const float* b4   = (const float*)d_in[14];
    float* out = (float*)d_out;

    // workspace layout
    float* xl1 = (float*)d_ws;                          // [N,256]
    float* xr1 = xl1 + (size_t)N_NODES*256;             // [N,256]
    float* h1  = xr1 + (size_t)N_NODES*256;             // [N,256]
    // layer-2 buffers overlay xl1 (dead after k_gat1)
    float* xl2 = xl1;                                   // [N,64]
    float* xr2 = xl2 + (size_t)N_NODES*64;              // [N,64]
    float* h2  = xr2 + (size_t)N_NODES*64;              // [N,64]
    int* rowptr  = (int*)(h1 + (size_t)N_NODES*256);    // [N+1]
    int* cursor  = rowptr + (N_NODES+1);                // [N]
    int* partial = cursor + N_NODES;                    // [64]
    int* srcs    = partial + 64;                        // [E]
    int* deg     = srcs + N_EDGES;                      // [N]

    hipMemsetAsync(deg, 0, (size_t)N_NODES*sizeof(int), stream);

    k_lin1<<<N_NODES/16, 256, 0, stream>>>(x, Wl1, Wr1, xl1, xr1);

    k_hist<<<N_EDGES/256, 256, 0, stream>>>(ei, deg);
    const int SCAN_BLKS = (N_NODES + 1023) / 1024;      // 49
    k_scan_a<<<SCAN_BLKS, 1024, 0, stream>>>(deg, rowptr, partial);
    k_scan_c<<<SCAN_BLKS, 1024, 0, stream>>>(rowptr, cursor, partial);
    k_scatter<<<N_EDGES/256, 256, 0, stream>>>(ei, cursor, srcs);

    k_gat1<<<N_NODES, 256, 0, stream>>>(xl1, xr1, srcs, rowptr, att1, b1, h1);
    k_lin2<<<N_NODES/16, 128, 0, stream>>>(h1, Wl2, Wr2, xl2, xr2);
    k_gat2<<<N_NODES/4, 256, 0, stream>>>(xl2, xr2, srcs, rowptr, att2, b2, h2);
    k_poolmlp<<<N_GRAPHS, 256, 0, stream>>>(h2, batch, W3, b3, W4, b4, out);
}

// Round 3
// 450.660 us; speedup vs baseline: 1.7731x; 1.0273x over previous
//
#include <hip/hip_runtime.h>
#include <math.h>

#define N_NODES 50000
#define N_EDGES 800000
#define N_GRAPHS 64

__device__ __forceinline__ float leaky(float v){
    return fmaf(0.2f, fminf(v, 0.f), fmaxf(v, 0.f));
}
__device__ __forceinline__ float elu1(float v){ return v > 0.f ? v : expm1f(v); }

// ---- lin1: xl = x@Wl, xr = x@Wr ; x [N,64], W [64,256] -> out [N,256]
__global__ __launch_bounds__(256) void k_lin1(const float* __restrict__ x,
        const float* __restrict__ Wl, const float* __restrict__ Wr,
        float* __restrict__ xl, float* __restrict__ xr){
    __shared__ float xs[16][64];
    int t = threadIdx.x;
    size_t n0 = (size_t)blockIdx.x * 16;
    const float4* xg = (const float4*)(x + n0*64);   // 1024 floats = 256 float4
    ((float4*)xs)[t] = xg[t];
    __syncthreads();
    float accl[16], accr[16];
    #pragma unroll
    for (int m=0;m<16;m++){ accl[m]=0.f; accr[m]=0.f; }
    for (int k=0;k<64;k++){
        float wl = Wl[k*256+t], wr = Wr[k*256+t];
        #pragma unroll
        for (int m=0;m<16;m++){ float xv = xs[m][k]; accl[m]=fmaf(xv,wl,accl[m]); accr[m]=fmaf(xv,wr,accr[m]); }
    }
    for (int m=0;m<16;m++){
        xl[(n0+m)*256+t]=accl[m];
        xr[(n0+m)*256+t]=accr[m];
    }
}

// ---- lin2: h [N,256] (already bias+ELU'd), W [256,64] -> out [N,64]
__global__ __launch_bounds__(128) void k_lin2(const float* __restrict__ h,
        const float* __restrict__ Wl, const float* __restrict__ Wr,
        float* __restrict__ xl, float* __restrict__ xr){
    __shared__ float hs[16][256];
    int t = threadIdx.x;
    size_t n0 = (size_t)blockIdx.x * 16;
    const float4* hg = (const float4*)(h + n0*256);  // 4096 floats = 1024 float4
    #pragma unroll
    for (int i=0;i<8;i++) ((float4*)hs)[t + 128*i] = hg[t + 128*i];
    __syncthreads();
    const float* W = (t < 64) ? Wl : Wr;
    float* o = (t < 64) ? xl : xr;
    int col = t & 63;
    float acc[16];
    #pragma unroll
    for (int m=0;m<16;m++) acc[m]=0.f;
    for (int k=0;k<256;k++){
        float w = W[k*64+col];
        #pragma unroll
        for (int m=0;m<16;m++) acc[m]=fmaf(hs[m][k],w,acc[m]);
    }
    for (int m=0;m<16;m++) o[(n0+m)*64+col]=acc[m];
}

// ---- CSR build over dst (srcs stored directly)
__global__ void k_hist(const int* __restrict__ ei, int* __restrict__ deg){
    int e = blockIdx.x*256 + threadIdx.x;
    if (e < N_EDGES) atomicAdd(&deg[ei[N_EDGES + e]], 1);
}

__global__ __launch_bounds__(1024) void k_scan_a(const int* __restrict__ deg,
        int* __restrict__ rowptr, int* __restrict__ partial){
    __shared__ int s[1024];
    int t = threadIdx.x; int i = blockIdx.x*1024 + t;
    int v = (i < N_NODES) ? deg[i] : 0;
    s[t] = v; __syncthreads();
    for (int off=1; off<1024; off<<=1){
        int add = (t>=off) ? s[t-off] : 0;
        __syncthreads();
        s[t] += add;
        __syncthreads();
    }
    if (i < N_NODES) rowptr[i] = s[t] - v;   // local exclusive
    if (t == 1023) partial[blockIdx.x] = s[1023];   // block total
}

__global__ __launch_bounds__(1024) void k_scan_c(int* __restrict__ rowptr,
        int* __restrict__ cursor, const int* __restrict__ partial){
    __shared__ int base;
    if (threadIdx.x == 0){
        int run = 0;
        for (int bk=0; bk<(int)blockIdx.x; bk++) run += partial[bk];
        base = run;
    }
    __syncthreads();
    int i = blockIdx.x*1024 + threadIdx.x;
    if (i < N_NODES){
        int r = rowptr[i] + base;
        rowptr[i] = r; cursor[i] = r;
    } else if (i == N_NODES){
        rowptr[N_NODES] = N_EDGES;
    }
}

__global__ void k_scatter(const int* __restrict__ ei, int* __restrict__ cursor,
                          int* __restrict__ srcs){
    int e = blockIdx.x*256 + threadIdx.x;
    if (e < N_EDGES){
        int d = ei[N_EDGES + e];
        int pos = atomicAdd(&cursor[d], 1);
        srcs[pos] = ei[e];                    // store SRC directly
    }
}

// ---- fused GAT layer 1: one WAVE per dst node, 4 nodes per 256-thr block.
// Lane l holds channels [4l,4l+3] (float4); head = l>>4; dot-reduce = 4 shfl
// steps within 16-lane groups. 4 edges in flight per wave (ILP unroll).
__global__ __launch_bounds__(256) void k_gat1(const float* __restrict__ xl,
        const float* __restrict__ xr, const int* __restrict__ srcs,
        const int* __restrict__ rowptr,
        const float* __restrict__ att, const float* __restrict__ b,
        float* __restrict__ h1){
    int w = threadIdx.x >> 6, l = threadIdx.x & 63;
    int n = blockIdx.x*4 + w;
    float4 xr4  = ((const float4*)(xr + (size_t)n*256))[l];
    float4 att4 = ((const float4*)att)[l];
    float4 acc = make_float4(0.f,0.f,0.f,0.f);
    float dacc = 0.f;
    int beg = rowptr[n], end = rowptr[n+1];
    const float4* xl4 = (const float4*)xl;
    for (int j = beg; j < end; j += 4){
        bool a1 = j+1 < end, a2 = j+2 < end, a3 = j+3 < end;
        int s0 = srcs[j];
        int s1 = a1 ? srcs[j+1] : s0;
        int s2 = a2 ? srcs[j+2] : s0;
        int s3 = a3 ? srcs[j+3] : s0;
        float4 x0 = xl4[((unsigned)s0<<6) + l];
        float4 x1 = xl4[((unsigned)s1<<6) + l];
        float4 x2 = xl4[((unsigned)s2<<6) + l];
        float4 x3 = xl4[((unsigned)s3<<6) + l];
        float p0 =      leaky(x0.x + xr4.x) * att4.x;
        p0 = fmaf(leaky(x0.y + xr4.y), att4.y, p0);
        p0 = fmaf(leaky(x0.z + xr4.z), att4.z, p0);
        p0 = fmaf(leaky(x0.w + xr4.w), att4.w, p0);
        float p1 =      leaky(x1.x + xr4.x) * att4.x;
        p1 = fmaf(leaky(x1.y + xr4.y), att4.y, p1);
        p1 = fmaf(leaky(x1.z + xr4.z), att4.z, p1);
        p1 = fmaf(leaky(x1.w + xr4.w), att4.w, p1);
        float p2 =      leaky(x2.x + xr4.x) * att4.x;
        p2 = fmaf(leaky(x2.y + xr4.y), att4.y, p2);
        p2 = fmaf(leaky(x2.z + xr4.z), att4.z, p2);
        p2 = fmaf(leaky(x2.w + xr4.w), att4.w, p2);
        float p3 =      leaky(x3.x + xr4.x) * att4.x;
        p3 = fmaf(leaky(x3.y + xr4.y), att4.y, p3);
        p3 = fmaf(leaky(x3.z + xr4.z), att4.z, p3);
        p3 = fmaf(leaky(x3.w + xr4.w), att4.w, p3);
        #pragma unroll
        for (int off=1; off<16; off<<=1){
            p0 += __shfl_xor(p0, off);
            p1 += __shfl_xor(p1, off);
            p2 += __shfl_xor(p2, off);
            p3 += __shfl_xor(p3, off);
        }
        float e0 = __expf(p0);
        float e1 = a1 ? __expf(p1) : 0.f;
        float e2 = a2 ? __expf(p2) : 0.f;
        float e3 = a3 ? __expf(p3) : 0.f;
        acc.x = fmaf(e0,x0.x, fmaf(e1,x1.x, fmaf(e2,x2.x, fmaf(e3,x3.x, acc.x))));
        acc.y = fmaf(e0,x0.y, fmaf(e1,x1.y, fmaf(e2,x2.y, fmaf(e3,x3.y, acc.y))));
        acc.z = fmaf(e0,x0.z, fmaf(e1,x1.z, fmaf(e2,x2.z, fmaf(e3,x3.z, acc.z))));
        acc.w = fmaf(e0,x0.w, fmaf(e1,x1.w, fmaf(e2,x2.w, fmaf(e3,x3.w, acc.w))));
        dacc += e0 + e1 + e2 + e3;
    }
    float inv = 1.f / (dacc + 1e-16f);
    float4 b4 = ((const float4*)b)[l];
    float4 o;
    o.x = elu1(fmaf(acc.x, inv, b4.x));
    o.y = elu1(fmaf(acc.y, inv, b4.y));
    o.z = elu1(fmaf(acc.z, inv, b4.z));
    o.w = elu1(fmaf(acc.w, inv, b4.w));
    ((float4*)(h1 + (size_t)n*256))[l] = o;
}

// ---- fused GAT layer 2: one wave per node; 8 edge-slots per wave
// (4 groups of 16 lanes x 2-deep unroll; 16 lanes x float4 = 64 ch per edge).
__global__ __launch_bounds__(256) void k_gat2(const float* __restrict__ xl,
        const float* __restrict__ xr, const int* __restrict__ srcs,
        const int* __restrict__ rowptr,
        const float* __restrict__ att, const float* __restrict__ b,
        float* __restrict__ h2){
    int w = threadIdx.x >> 6, l = threadIdx.x & 63;
    int n = blockIdx.x*4 + w;
    int g = l >> 4, sub = l & 15;
    float4 xr4  = ((const float4*)(xr + (size_t)n*64))[sub];
    float4 att4 = ((const float4*)att)[sub];
    float4 acc = make_float4(0.f,0.f,0.f,0.f);
    float dacc = 0.f;
    int beg = rowptr[n], end = rowptr[n+1];
    const float4* xl4 = (const float4*)xl;
    for (int j = beg; j < end; j += 8){
        int j1 = j + g, j2 = j + 4 + g;
        bool a1 = j1 < end, a2 = j2 < end;
        int s1 = a1 ? srcs[j1] : srcs[beg];
        int s2 = a2 ? srcs[j2] : srcs[beg];
        float4 y1 = xl4[((unsigned)s1<<4) + sub];
        float4 y2 = xl4[((unsigned)s2<<4) + sub];
        float p1 =      leaky(y1.x + xr4.x) * att4.x;
        p1 = fmaf(leaky(y1.y + xr4.y), att4.y, p1);
        p1 = fmaf(leaky(y1.z + xr4.z), att4.z, p1);
        p1 = fmaf(leaky(y1.w + xr4.w), att4.w, p1);
        float p2 =      leaky(y2.x + xr4.x) * att4.x;
        p2 = fmaf(leaky(y2.y + xr4.y), att4.y, p2);
        p2 = fmaf(leaky(y2.z + xr4.z), att4.z, p2);
        p2 = fmaf(leaky(y2.w + xr4.w), att4.w, p2);
        #pragma unroll
        for (int off=1; off<16; off<<=1){
            p1 += __shfl_xor(p1, off);
            p2 += __shfl_xor(p2, off);
        }
        float e1 = a1 ? __expf(p1) : 0.f;
        float e2 = a2 ? __expf(p2) : 0.f;
        acc.x = fmaf(e1, y1.x, fmaf(e2, y2.x, acc.x));
        acc.y = fmaf(e1, y1.y, fmaf(e2, y2.y, acc.y));
        acc.z = fmaf(e1, y1.z, fmaf(e2, y2.z, acc.z));
        acc.w = fmaf(e1, y1.w, fmaf(e2, y2.w, acc.w));
        dacc += e1 + e2;
    }
    // combine the 4 groups (lanes differing in bits 4,5)
    #pragma unroll
    for (int off=16; off<64; off<<=1){
        acc.x += __shfl_xor(acc.x, off);
        acc.y += __shfl_xor(acc.y, off);
        acc.z += __shfl_xor(acc.z, off);
        acc.w += __shfl_xor(acc.w, off);
        dacc  += __shfl_xor(dacc,  off);
    }
    if (g == 0){
        float inv = 1.f / (dacc + 1e-16f);
        float4 b4 = ((const float4*)b)[sub];
        float4 o;
        o.x = elu1(fmaf(acc.x, inv, b4.x));
        o.y = elu1(fmaf(acc.y, inv, b4.y));
        o.z = elu1(fmaf(acc.z, inv, b4.z));
        o.w = elu1(fmaf(acc.w, inv, b4.w));
        ((float4*)(h2 + (size_t)n*64))[sub] = o;
    }
}

__device__ __forceinline__ int lower_bound_i(const int* a, int n, int key){
    int lo = 0, hi = n;
    while (lo < hi){ int mid = (lo+hi)>>1; if (a[mid] < key) lo = mid+1; else hi = mid; }
    return lo;
}

// ---- global mean pool + MLP head fused: one block per graph (batch sorted)
__global__ __launch_bounds__(256) void k_poolmlp(const float* __restrict__ h2,
        const int* __restrict__ batch,
        const float* __restrict__ W3, const float* __restrict__ b3,
        const float* __restrict__ W4, const float* __restrict__ b4,
        float* __restrict__ out){
    int g = blockIdx.x, t = threadIdx.x;
    int c = t & 63, q = t >> 6;
    int start = lower_bound_i(batch, N_NODES, g);
    int end   = lower_bound_i(batch, N_NODES, g+1);
    float s = 0.f;
    for (int i = start + q; i < end; i += 4) s += h2[(size_t)i*64 + c];
    __shared__ float red[256];
    __shared__ float ps[64], zs[64];
    red[t] = s; __syncthreads();
    if (q == 0){
        float tot = red[c] + red[64+c] + red[128+c] + red[192+c];
        ps[c] = tot / fmaxf((float)(end - start), 1.f);
    }
    __syncthreads();
    if (q == 0){
        float a = b3[c];
        for (int k=0;k<64;k++) a = fmaf(ps[k], W3[k*64+c], a);
        zs[c] = fmaxf(a, 0.f);
    }
    __syncthreads();
    if (t < 2){
        float o = b4[t];
        for (int k=0;k<64;k++) o = fmaf(zs[k], W4[k*2+t], o);
        out[g*2 + t] = o;
    }
}

extern "C" void kernel_launch(void* const* d_in, const int* in_sizes, int n_in,
                              void* d_out, int out_size, void* d_ws, size_t ws_size,
                              hipStream_t stream) {
    const float* x    = (const float*)d_in[0];
    const int*   ei   = (const int*)  d_in[1];   // [2, E] flat
    const int*   batch= (const int*)  d_in[2];
    const float* Wl1  = (const float*)d_in[3];
    const float* Wr1  = (const float*)d_in[4];
    const float* att1 = (const float*)d_in[5];
    const float* b1   = (const float*)d_in[6];
    const float* Wl2  = (const float*)d_in[7];
    const float* Wr2  = (const float*)d_in[8];
    const float* att2 = (const float*)d_in[9];
    const float* b2   = (const float*)d_in[10];
    const float* W3   = (const float*)d_in[11];
    const float* b3   = (const float*)d_in[12];
    const float* W4   = (const float*)d_in[13];
    const float* b4   = (const float*)d_in[14];
    float* out = (float*)d_out;

    // workspace layout
    float* xl1 = (float*)d_ws;                          // [N,256]
    float* xr1 = xl1 + (size_t)N_NODES*256;             // [N,256]
    float* h1  = xr1 + (size_t)N_NODES*256;             // [N,256]
    // layer-2 buffers overlay xl1 (dead after k_gat1)
    float* xl2 = xl1;                                   // [N,64]
    float* xr2 = xl2 + (size_t)N_NODES*64;              // [N,64]
    float* h2  = xr2 + (size_t)N_NODES*64;              // [N,64]
    int* rowptr  = (int*)(h1 + (size_t)N_NODES*256);    // [N+1]
    int* cursor  = rowptr + (N_NODES+1);                // [N]
    int* partial = cursor + N_NODES;                    // [64]
    int* srcs    = partial + 64;                        // [E]
    int* deg     = srcs + N_EDGES;                      // [N]

    hipMemsetAsync(deg, 0, (size_t)N_NODES*sizeof(int), stream);

    k_lin1<<<N_NODES/16, 256, 0, stream>>>(x, Wl1, Wr1, xl1, xr1);

    k_hist<<<N_EDGES/256, 256, 0, stream>>>(ei, deg);
    const int SCAN_BLKS = (N_NODES + 1023) / 1024;      // 49
    k_scan_a<<<SCAN_BLKS, 1024, 0, stream>>>(deg, rowptr, partial);
    k_scan_c<<<SCAN_BLKS, 1024, 0, stream>>>(rowptr, cursor, partial);
    k_scatter<<<N_EDGES/256, 256, 0, stream>>>(ei, cursor, srcs);

    k_gat1<<<N_NODES/4, 256, 0, stream>>>(xl1, xr1, srcs, rowptr, att1, b1, h1);
    k_lin2<<<N_NODES/16, 128, 0, stream>>>(h1, Wl2, Wr2, xl2, xr2);
    k_gat2<<<N_NODES/4, 256, 0, stream>>>(xl2, xr2, srcs, rowptr, att2, b2, h2);
    k_poolmlp<<<N_GRAPHS, 256, 0, stream>>>(h2, batch, W3, b3, W4, b4, out);
}